// Round 1
// baseline (877.906 us; speedup 1.0000x reference)
//
#include <hip/hip_runtime.h>
#include <cstdint>
#include <cstddef>

// ---------------- common helpers ----------------

#define GAS __attribute__((address_space(1)))
#define LAS __attribute__((address_space(3)))

typedef __bf16 bf16x8 __attribute__((ext_vector_type(8)));
typedef float  f32x4  __attribute__((ext_vector_type(4)));

__device__ __forceinline__ unsigned short f2bf(float f) {
    // round-to-nearest-even float -> bf16 bits (finite inputs only)
    unsigned int u = __float_as_uint(f);
    u += 0x7FFFu + ((u >> 16) & 1u);
    return (unsigned short)(u >> 16);
}
__device__ __forceinline__ float bf2f(unsigned short h) {
    return __uint_as_float(((unsigned int)h) << 16);
}

// ---------------- problem constants ----------------
// B=4096, S=128, E=1024, H=4096, H2=2048, NCLS=3
static constexpr int BB = 4096;
static constexpr int SS = 128;
static constexpr int EE = 1024;
static constexpr int HH = 4096;
static constexpr int H2D = 2048;

// workspace layout (bytes)
static constexpr size_t OFF_S  = 0;                         // 3 doubles (abs-sums)
static constexpr size_t OFF_Q1 = 256;                       // 4096x1024 ushort = 8 MB
static constexpr size_t SZ_Q1  = (size_t)HH * EE * 2;
static constexpr size_t OFF_X  = OFF_Q1 + SZ_Q1;            // 4096x1024 ushort = 8 MB
static constexpr size_t SZ_X   = (size_t)BB * EE * 2;
static constexpr size_t OFF_Q2 = OFF_X + SZ_X;              // 2048x4096 ushort = 16 MB
static constexpr size_t SZ_Q2  = (size_t)H2D * HH * 2;
static constexpr size_t OFF_Q3 = OFF_Q2 + SZ_Q2;            // 3x2048 float
static constexpr size_t SZ_Q3  = (size_t)3 * H2D * 4;
static constexpr size_t OFF_C  = OFF_Q3 + SZ_Q3;            // 4096x4096 fp32 = 64 MB (C1, reused as C2)
static constexpr size_t SZ_C   = (size_t)BB * HH * 4;
static constexpr size_t OFF_H1 = OFF_C + SZ_C;              // 4096x4096 ushort = 32 MB
// H2 (4096x2048 ushort = 16 MB) overlays q1+X, both dead after GEMM1
static constexpr size_t OFF_H2 = OFF_Q1;

// ---------------- kernels ----------------

__global__ void zero_sums(double* s) {
    if (threadIdx.x < 3) s[threadIdx.x] = 0.0;
}

__global__ __launch_bounds__(256) void absum_kernel(const float* __restrict__ w, int n,
                                                    double* __restrict__ out) {
    const int tid = threadIdx.x;
    const int lane = tid & 63, wid = tid >> 6;
    double acc = 0.0;
    for (int i = blockIdx.x * 256 + tid; i < n; i += gridDim.x * 256)
        acc += (double)fabsf(w[i]);
    for (int o = 32; o; o >>= 1) acc += __shfl_down(acc, o);
    __shared__ double r[4];
    if (lane == 0) r[wid] = acc;
    __syncthreads();
    if (tid == 0) atomicAdd(out, r[0] + r[1] + r[2] + r[3]);
}

__global__ __launch_bounds__(256) void quant_bf16_kernel(const float* __restrict__ w,
                                                         const double* __restrict__ ssum, int n,
                                                         unsigned short* __restrict__ q) {
    const float inv_s = (float)((double)n / ssum[0]);
    for (int i = blockIdx.x * 256 + threadIdx.x; i < n; i += gridDim.x * 256) {
        float t = w[i] * inv_s;
        t = fminf(1.f, fmaxf(-1.f, t));
        q[i] = f2bf(rintf(t));     // exactly -1/0/+1 in bf16
    }
}

__global__ __launch_bounds__(256) void quant_f32_kernel(const float* __restrict__ w,
                                                        const double* __restrict__ ssum, int n,
                                                        float* __restrict__ q) {
    const float inv_s = (float)((double)n / ssum[0]);
    for (int i = blockIdx.x * 256 + threadIdx.x; i < n; i += gridDim.x * 256) {
        float t = w[i] * inv_s;
        t = fminf(1.f, fmaxf(-1.f, t));
        q[i] = rintf(t);
    }
}

// embedding gather + masked mean pool; one block per output row
__global__ __launch_bounds__(256) void pool_kernel(const int* __restrict__ ids,
                                                   const float* __restrict__ emb,
                                                   unsigned short* __restrict__ X) {
    const int b = blockIdx.x;
    const int tid = threadIdx.x;
    __shared__ int sid[SS];
    if (tid < SS) sid[tid] = ids[(size_t)b * SS + tid];
    __syncthreads();
    const int col = tid * 4;
    float a0 = 0.f, a1 = 0.f, a2 = 0.f, a3 = 0.f;
    int cnt = 0;
    #pragma unroll 8
    for (int s = 0; s < SS; ++s) {
        const int id = sid[s];
        if (id != 0) {               // wave-uniform branch
            const float4 v = *(const float4*)(emb + (size_t)id * EE + col);
            a0 += v.x; a1 += v.y; a2 += v.z; a3 += v.w;
            cnt++;
        }
    }
    const float inv = 1.f / (float)(cnt > 0 ? cnt : 1);
    union { ushort4 u; unsigned short h[4]; } o;
    o.h[0] = f2bf(a0 * inv); o.h[1] = f2bf(a1 * inv);
    o.h[2] = f2bf(a2 * inv); o.h[3] = f2bf(a3 * inv);
    *(ushort4*)(X + (size_t)b * EE + col) = o.u;
}

// C[M,N] = A[M,K] * B[N,K]^T  (bf16 in, fp32 out). M%128==0, N%128==0, K%32==0.
// m97 structure: 128x128 tile, BK=32, global_load_lds width 16, 4 waves x (4x4) 16x16x32 MFMA.
__global__ __launch_bounds__(256) void gemm_bt(const unsigned short* __restrict__ A,
                                               const unsigned short* __restrict__ B,
                                               float* __restrict__ C, int M, int N, int K) {
    __shared__ unsigned short sA[128 * 32];
    __shared__ unsigned short sB[128 * 32];
    const int tid  = threadIdx.x;
    const int wid  = tid >> 6;
    const int lane = tid & 63;
    const int wm = wid >> 1, wn = wid & 1;
    const int quad = lane >> 4;
    const int l16  = lane & 15;
    const int mBase = blockIdx.y * 128;
    const int nBase = blockIdx.x * 128;

    f32x4 acc[4][4] = {};

    // staging: thread tid covers tile bytes (round*4096 + tid*16)
    const int srow = tid >> 2;            // 0..63
    const int scol = (tid & 3) * 8;       // element col within BK=32
    const size_t aOff0 = (size_t)(mBase + srow) * K + scol;
    const size_t aOff1 = aOff0 + (size_t)64 * K;
    const size_t bOff0 = (size_t)(nBase + srow) * K + scol;
    const size_t bOff1 = bOff0 + (size_t)64 * K;
    unsigned short* ldsA0 = &sA[wid * 512];
    unsigned short* ldsA1 = &sA[2048 + wid * 512];
    unsigned short* ldsB0 = &sB[wid * 512];
    unsigned short* ldsB1 = &sB[2048 + wid * 512];

    for (int k0 = 0; k0 < K; k0 += 32) {
        __syncthreads();   // previous iteration's ds_reads done before overwrite
        __builtin_amdgcn_global_load_lds((const GAS void*)(A + aOff0 + k0), (LAS void*)ldsA0, 16, 0, 0);
        __builtin_amdgcn_global_load_lds((const GAS void*)(A + aOff1 + k0), (LAS void*)ldsA1, 16, 0, 0);
        __builtin_amdgcn_global_load_lds((const GAS void*)(B + bOff0 + k0), (LAS void*)ldsB0, 16, 0, 0);
        __builtin_amdgcn_global_load_lds((const GAS void*)(B + bOff1 + k0), (LAS void*)ldsB1, 16, 0, 0);
        __syncthreads();   // staging visible (compiler drains vmcnt before barrier)

        bf16x8 af[4], bfr[4];
        #pragma unroll
        for (int i = 0; i < 4; ++i) {
            const int rowA = wm * 64 + i * 16 + l16;
            af[i]  = *(const bf16x8*)(&sA[rowA * 32 + quad * 8]);
            const int rowB = wn * 64 + i * 16 + l16;
            bfr[i] = *(const bf16x8*)(&sB[rowB * 32 + quad * 8]);
        }
        #pragma unroll
        for (int i = 0; i < 4; ++i)
            #pragma unroll
            for (int j = 0; j < 4; ++j)
                acc[i][j] = __builtin_amdgcn_mfma_f32_16x16x32_bf16(af[i], bfr[j], acc[i][j], 0, 0, 0);
    }

    // epilogue: C/D layout col=lane&15, row=(lane>>4)*4+reg
    #pragma unroll
    for (int i = 0; i < 4; ++i) {
        const int row0 = mBase + wm * 64 + i * 16 + quad * 4;
        #pragma unroll
        for (int j = 0; j < 4; ++j) {
            const int col = nBase + wn * 64 + j * 16 + l16;
            #pragma unroll
            for (int r = 0; r < 4; ++r)
                C[(size_t)(row0 + r) * N + col] = acc[i][j][r];
        }
    }
}

// y = C*s + bias; layernorm over row; gelu(exact); write bf16
__global__ __launch_bounds__(256) void ln_gelu_kernel(const float* __restrict__ Cm,
                                                      const double* __restrict__ ssum, double nw,
                                                      const float* __restrict__ bias,
                                                      const float* __restrict__ gamma,
                                                      const float* __restrict__ beta,
                                                      unsigned short* __restrict__ H, int N) {
    __shared__ float buf[4096];
    __shared__ float redS[4], redQ[4];
    const int row = blockIdx.x, tid = threadIdx.x;
    const int lane = tid & 63, wid = tid >> 6;
    const float s = (float)(ssum[0] / nw);
    float ps = 0.f, pq = 0.f;
    for (int c = tid; c < N; c += 256) {
        const float y = Cm[(size_t)row * N + c] * s + bias[c];
        buf[c] = y;
        ps += y; pq += y * y;
    }
    for (int o = 32; o; o >>= 1) { ps += __shfl_down(ps, o); pq += __shfl_down(pq, o); }
    if (lane == 0) { redS[wid] = ps; redQ[wid] = pq; }
    __syncthreads();
    const float sum = redS[0] + redS[1] + redS[2] + redS[3];
    const float sq  = redQ[0] + redQ[1] + redQ[2] + redQ[3];
    const float mu  = sum / (float)N;
    float var = sq / (float)N - mu * mu;
    var = fmaxf(var, 0.f);
    const float inv = rsqrtf(var + 1e-5f);
    for (int c = tid; c < N; c += 256) {
        const float y = (buf[c] - mu) * inv * gamma[c] + beta[c];
        const float g = 0.5f * y * (1.f + erff(y * 0.70710678118654752f));
        H[(size_t)row * N + c] = f2bf(g);
    }
}

// logits[row, 0..2] = H2[row,:] . q3[c,:] * s3 + b3
__global__ __launch_bounds__(256) void final_kernel(const unsigned short* __restrict__ H2,
                                                    const float* __restrict__ q3,
                                                    const double* __restrict__ ssum,
                                                    const float* __restrict__ b3,
                                                    float* __restrict__ out) {
    const int row = blockIdx.x, tid = threadIdx.x;
    const int lane = tid & 63, wid = tid >> 6;
    float a0 = 0.f, a1 = 0.f, a2 = 0.f;
    for (int k = tid; k < H2D; k += 256) {
        const float h = bf2f(H2[(size_t)row * H2D + k]);
        a0 += h * q3[k];
        a1 += h * q3[H2D + k];
        a2 += h * q3[2 * H2D + k];
    }
    for (int o = 32; o; o >>= 1) {
        a0 += __shfl_down(a0, o); a1 += __shfl_down(a1, o); a2 += __shfl_down(a2, o);
    }
    __shared__ float r[3][4];
    if (lane == 0) { r[0][wid] = a0; r[1][wid] = a1; r[2][wid] = a2; }
    __syncthreads();
    if (tid < 3) {
        const float s3 = (float)(ssum[0] / (double)(3 * H2D));
        out[(size_t)row * 3 + tid] =
            (r[tid][0] + r[tid][1] + r[tid][2] + r[tid][3]) * s3 + b3[tid];
    }
}

// ---------------- launch ----------------

extern "C" void kernel_launch(void* const* d_in, const int* in_sizes, int n_in,
                              void* d_out, int out_size, void* d_ws, size_t ws_size,
                              hipStream_t stream) {
    const int*   ids = (const int*)d_in[0];
    const float* emb = (const float*)d_in[1];
    const float* w1  = (const float*)d_in[2];
    const float* b1  = (const float*)d_in[3];
    const float* w2  = (const float*)d_in[4];
    const float* b2  = (const float*)d_in[5];
    const float* w3  = (const float*)d_in[6];
    const float* b3  = (const float*)d_in[7];
    const float* g1  = (const float*)d_in[8];
    const float* be1 = (const float*)d_in[9];
    const float* g2  = (const float*)d_in[10];
    const float* be2 = (const float*)d_in[11];
    float* out = (float*)d_out;
    char* ws = (char*)d_ws;

    double*         sums = (double*)(ws + OFF_S);
    unsigned short* q1   = (unsigned short*)(ws + OFF_Q1);
    unsigned short* X    = (unsigned short*)(ws + OFF_X);
    unsigned short* q2   = (unsigned short*)(ws + OFF_Q2);
    float*          q3   = (float*)(ws + OFF_Q3);
    float*          Cbuf = (float*)(ws + OFF_C);
    unsigned short* H1   = (unsigned short*)(ws + OFF_H1);
    unsigned short* H2   = (unsigned short*)(ws + OFF_H2);

    zero_sums<<<1, 64, 0, stream>>>(sums);
    absum_kernel<<<1024, 256, 0, stream>>>(w1, HH * EE, sums + 0);
    absum_kernel<<<2048, 256, 0, stream>>>(w2, H2D * HH, sums + 1);
    absum_kernel<<<24, 256, 0, stream>>>(w3, 3 * H2D, sums + 2);

    quant_bf16_kernel<<<4096, 256, 0, stream>>>(w1, sums + 0, HH * EE, q1);
    quant_bf16_kernel<<<8192, 256, 0, stream>>>(w2, sums + 1, H2D * HH, q2);
    quant_f32_kernel<<<24, 256, 0, stream>>>(w3, sums + 2, 3 * H2D, q3);

    pool_kernel<<<BB, 256, 0, stream>>>(ids, emb, X);

    gemm_bt<<<dim3(HH / 128, BB / 128), 256, 0, stream>>>(X, q1, Cbuf, BB, HH, EE);
    ln_gelu_kernel<<<BB, 256, 0, stream>>>(Cbuf, sums + 0, (double)HH * (double)EE,
                                           b1, g1, be1, H1, HH);
    gemm_bt<<<dim3(H2D / 128, BB / 128), 256, 0, stream>>>(H1, q2, Cbuf, BB, H2D, HH);
    ln_gelu_kernel<<<BB, 256, 0, stream>>>(Cbuf, sums + 1, (double)H2D * (double)HH,
                                           b2, g2, be2, H2, H2D);
    final_kernel<<<BB, 256, 0, stream>>>(H2, q3, sums + 2, b3, out);
}

// Round 2
// 771.736 us; speedup vs baseline: 1.1376x; 1.1376x over previous
//
#include <hip/hip_runtime.h>
#include <cstdint>
#include <cstddef>

// ---------------- common helpers ----------------

#define GAS __attribute__((address_space(1)))
#define LAS __attribute__((address_space(3)))

typedef __bf16 bf16x8 __attribute__((ext_vector_type(8)));
typedef float  f32x4  __attribute__((ext_vector_type(4)));
typedef unsigned short u16x8 __attribute__((ext_vector_type(8)));

__device__ __forceinline__ unsigned short f2bf(float f) {
    // round-to-nearest-even float -> bf16 bits (finite inputs only)
    unsigned int u = __float_as_uint(f);
    u += 0x7FFFu + ((u >> 16) & 1u);
    return (unsigned short)(u >> 16);
}
__device__ __forceinline__ float bf2f(unsigned short h) {
    return __uint_as_float(((unsigned int)h) << 16);
}

// ---------------- problem constants ----------------
// B=4096, S=128, E=1024, H=4096, H2=2048, NCLS=3, VOCAB=50257
static constexpr int BB = 4096;
static constexpr int SS = 128;
static constexpr int EE = 1024;
static constexpr int HH = 4096;
static constexpr int H2D = 2048;
static constexpr int VOCAB = 50257;

// ---------------- workspace layout (bytes) ----------------
// Phase overlay: embh (bf16 table, 98.2 MiB) is dead after pool_kernel;
// q1/q2/C overlay it (88 MiB <= 98.2 MiB). H2 overlays q1/q2 (dead after gemm2).
static constexpr size_t OFF_S    = 0;                          // 3 doubles
static constexpr size_t OFF_X    = 4096;                       // 4096x1024 bf16 = 8 MiB
static constexpr size_t SZ_X     = (size_t)BB * EE * 2;
static constexpr size_t OFF_EMBH = OFF_X + SZ_X;               // 50257x1024 bf16 = 98.2 MiB
static constexpr size_t SZ_EMBH  = (size_t)VOCAB * EE * 2;
static constexpr size_t OFF_Q1   = OFF_EMBH;                   // 4096x1024 bf16 = 8 MiB
static constexpr size_t OFF_Q2   = OFF_Q1 + (size_t)HH * EE * 2;       // 2048x4096 bf16 = 16 MiB
static constexpr size_t OFF_C    = OFF_Q2 + (size_t)H2D * HH * 2;      // 4096x4096 f32 = 64 MiB
static constexpr size_t OFF_H1   = OFF_EMBH + SZ_EMBH;         // 4096x4096 bf16 = 32 MiB
static constexpr size_t OFF_H2   = OFF_Q1;                     // 4096x2048 bf16 = 16 MiB (overlay)
// total ws needed ~ 138.2 MiB

// ---------------- kernels ----------------

__global__ void zero_sums(double* s) {
    if (threadIdx.x < 3) s[threadIdx.x] = 0.0;
}

// fp32 emb table -> bf16 table (RNE), 8 elems/thread
__global__ __launch_bounds__(256) void emb2bf_kernel(const float* __restrict__ e,
                                                     unsigned short* __restrict__ o) {
    const int n8 = (VOCAB * EE) / 8;
    for (int i = blockIdx.x * 256 + threadIdx.x; i < n8; i += gridDim.x * 256) {
        const float4 v0 = ((const float4*)e)[2 * i];
        const float4 v1 = ((const float4*)e)[2 * i + 1];
        union { unsigned short u[8]; uint4 q; } r;
        r.u[0] = f2bf(v0.x); r.u[1] = f2bf(v0.y); r.u[2] = f2bf(v0.z); r.u[3] = f2bf(v0.w);
        r.u[4] = f2bf(v1.x); r.u[5] = f2bf(v1.y); r.u[6] = f2bf(v1.z); r.u[7] = f2bf(v1.w);
        ((uint4*)o)[i] = r.q;
    }
}

// abs-sum of all three weight tensors in one launch (fp64 accumulate)
__global__ __launch_bounds__(256) void absum_all(const float* __restrict__ w1,
                                                 const float* __restrict__ w2,
                                                 const float* __restrict__ w3,
                                                 double* __restrict__ sums) {
    const int bid = blockIdx.x;
    const float* w; int n; double* out; int b0; int nb;
    if (bid < 1024)      { w = w1; n = HH * EE;  out = sums + 0; b0 = bid;        nb = 1024; }
    else if (bid < 3072) { w = w2; n = H2D * HH; out = sums + 1; b0 = bid - 1024; nb = 2048; }
    else                 { w = w3; n = 3 * H2D;  out = sums + 2; b0 = bid - 3072; nb = 24;   }
    const int tid = threadIdx.x;
    const int lane = tid & 63, wid = tid >> 6;
    double acc = 0.0;
    for (int i = b0 * 256 + tid; i < n; i += nb * 256)
        acc += (double)fabsf(w[i]);
    for (int o = 32; o; o >>= 1) acc += __shfl_down(acc, o);
    __shared__ double r[4];
    if (lane == 0) r[wid] = acc;
    __syncthreads();
    if (tid == 0) atomicAdd(out, r[0] + r[1] + r[2] + r[3]);
}

// quantize w1 and w2 to ternary bf16 {-1,0,+1} in one launch
__global__ __launch_bounds__(256) void quant_all(const float* __restrict__ w1,
                                                 const float* __restrict__ w2,
                                                 const double* __restrict__ sums,
                                                 unsigned short* __restrict__ q1,
                                                 unsigned short* __restrict__ q2) {
    const int bid = blockIdx.x;
    const float* w; int n; unsigned short* q; int b0; int nb; double ssum; double dn;
    if (bid < 4096) { w = w1; n = HH * EE;  q = q1; b0 = bid;        nb = 4096; ssum = sums[0]; dn = (double)(HH) * EE; }
    else            { w = w2; n = H2D * HH; q = q2; b0 = bid - 4096; nb = 8192; ssum = sums[1]; dn = (double)(H2D) * HH; }
    const float inv_s = (float)(dn / ssum);
    for (int i = b0 * 256 + threadIdx.x; i < n; i += nb * 256) {
        float t = w[i] * inv_s;
        t = fminf(1.f, fmaxf(-1.f, t));
        q[i] = f2bf(rintf(t));     // exactly -1/0/+1 in bf16
    }
}

// bf16 embedding gather + masked mean pool; 2 output rows per block, branchless
// (row 0 of embh is all zeros, so id==0 loads contribute nothing)
__global__ __launch_bounds__(256) void pool_kernel(const int* __restrict__ ids,
                                                   const unsigned short* __restrict__ embh,
                                                   unsigned short* __restrict__ X) {
    const int tid  = threadIdx.x;
    const int half = tid >> 7;          // wave-uniform (waves 0-1 vs 2-3)
    const int t    = tid & 127;
    const int b    = blockIdx.x * 2 + half;
    __shared__ int sid[2 * SS];
    sid[tid] = ids[(size_t)blockIdx.x * 2 * SS + tid];
    __syncthreads();
    const int col  = t * 8;
    const int base = half * SS;
    float a[8] = {};
    int cnt = 0;
    #pragma unroll 8
    for (int s = 0; s < SS; ++s) {
        const int id = sid[base + s];
        cnt += (id != 0);
        const u16x8 v = *(const u16x8*)(embh + (size_t)id * EE + col);
        #pragma unroll
        for (int j = 0; j < 8; ++j) a[j] += bf2f(v[j]);
    }
    const float inv = 1.f / (float)(cnt ? cnt : 1);
    u16x8 o;
    #pragma unroll
    for (int j = 0; j < 8; ++j) o[j] = f2bf(a[j] * inv);
    *(u16x8*)(X + (size_t)b * EE + col) = o;
}

// C[M,N] = A[M,K] * B[N,K]^T  (bf16 in, fp32 out). M%128==0, N%128==0, K%32==0.
// m97 structure: 128x128 tile, BK=32, global_load_lds width 16, 4 waves x (4x4) 16x16x32 MFMA.
__global__ __launch_bounds__(256) void gemm_bt(const unsigned short* __restrict__ A,
                                               const unsigned short* __restrict__ B,
                                               float* __restrict__ C, int M, int N, int K) {
    __shared__ unsigned short sA[128 * 32];
    __shared__ unsigned short sB[128 * 32];
    const int tid  = threadIdx.x;
    const int wid  = tid >> 6;
    const int lane = tid & 63;
    const int wm = wid >> 1, wn = wid & 1;
    const int quad = lane >> 4;
    const int l16  = lane & 15;
    const int mBase = blockIdx.y * 128;
    const int nBase = blockIdx.x * 128;

    f32x4 acc[4][4] = {};

    const int srow = tid >> 2;            // 0..63
    const int scol = (tid & 3) * 8;       // element col within BK=32
    const size_t aOff0 = (size_t)(mBase + srow) * K + scol;
    const size_t aOff1 = aOff0 + (size_t)64 * K;
    const size_t bOff0 = (size_t)(nBase + srow) * K + scol;
    const size_t bOff1 = bOff0 + (size_t)64 * K;
    unsigned short* ldsA0 = &sA[wid * 512];
    unsigned short* ldsA1 = &sA[2048 + wid * 512];
    unsigned short* ldsB0 = &sB[wid * 512];
    unsigned short* ldsB1 = &sB[2048 + wid * 512];

    for (int k0 = 0; k0 < K; k0 += 32) {
        __syncthreads();
        __builtin_amdgcn_global_load_lds((const GAS void*)(A + aOff0 + k0), (LAS void*)ldsA0, 16, 0, 0);
        __builtin_amdgcn_global_load_lds((const GAS void*)(A + aOff1 + k0), (LAS void*)ldsA1, 16, 0, 0);
        __builtin_amdgcn_global_load_lds((const GAS void*)(B + bOff0 + k0), (LAS void*)ldsB0, 16, 0, 0);
        __builtin_amdgcn_global_load_lds((const GAS void*)(B + bOff1 + k0), (LAS void*)ldsB1, 16, 0, 0);
        __syncthreads();

        bf16x8 af[4], bfr[4];
        #pragma unroll
        for (int i = 0; i < 4; ++i) {
            const int rowA = wm * 64 + i * 16 + l16;
            af[i]  = *(const bf16x8*)(&sA[rowA * 32 + quad * 8]);
            const int rowB = wn * 64 + i * 16 + l16;
            bfr[i] = *(const bf16x8*)(&sB[rowB * 32 + quad * 8]);
        }
        #pragma unroll
        for (int i = 0; i < 4; ++i)
            #pragma unroll
            for (int j = 0; j < 4; ++j)
                acc[i][j] = __builtin_amdgcn_mfma_f32_16x16x32_bf16(af[i], bfr[j], acc[i][j], 0, 0, 0);
    }

    // epilogue: C/D layout col=lane&15, row=(lane>>4)*4+reg
    #pragma unroll
    for (int i = 0; i < 4; ++i) {
        const int row0 = mBase + wm * 64 + i * 16 + quad * 4;
        #pragma unroll
        for (int j = 0; j < 4; ++j) {
            const int col = nBase + wn * 64 + j * 16 + l16;
            #pragma unroll
            for (int r = 0; r < 4; ++r)
                C[(size_t)(row0 + r) * N + col] = acc[i][j][r];
        }
    }
}

// y = C*s + bias; layernorm over row; gelu(exact); write bf16
__global__ __launch_bounds__(256) void ln_gelu_kernel(const float* __restrict__ Cm,
                                                      const double* __restrict__ ssum, double nw,
                                                      const float* __restrict__ bias,
                                                      const float* __restrict__ gamma,
                                                      const float* __restrict__ beta,
                                                      unsigned short* __restrict__ H, int N) {
    __shared__ float buf[4096];
    __shared__ float redS[4], redQ[4];
    const int row = blockIdx.x, tid = threadIdx.x;
    const int lane = tid & 63, wid = tid >> 6;
    const float s = (float)(ssum[0] / nw);
    float ps = 0.f, pq = 0.f;
    for (int c = tid; c < N; c += 256) {
        const float y = Cm[(size_t)row * N + c] * s + bias[c];
        buf[c] = y;
        ps += y; pq += y * y;
    }
    for (int o = 32; o; o >>= 1) { ps += __shfl_down(ps, o); pq += __shfl_down(pq, o); }
    if (lane == 0) { redS[wid] = ps; redQ[wid] = pq; }
    __syncthreads();
    const float sum = redS[0] + redS[1] + redS[2] + redS[3];
    const float sq  = redQ[0] + redQ[1] + redQ[2] + redQ[3];
    const float mu  = sum / (float)N;
    float var = sq / (float)N - mu * mu;
    var = fmaxf(var, 0.f);
    const float inv = rsqrtf(var + 1e-5f);
    for (int c = tid; c < N; c += 256) {
        const float y = (buf[c] - mu) * inv * gamma[c] + beta[c];
        const float g = 0.5f * y * (1.f + erff(y * 0.70710678118654752f));
        H[(size_t)row * N + c] = f2bf(g);
    }
}

// logits[row, 0..2] = H2[row,:] . ternary(w3)[c,:] + b3  (w3 quantized on the fly)
__global__ __launch_bounds__(256) void final_kernel(const unsigned short* __restrict__ H2,
                                                    const float* __restrict__ w3,
                                                    const double* __restrict__ ssum,
                                                    const float* __restrict__ b3,
                                                    float* __restrict__ out) {
    const int row = blockIdx.x, tid = threadIdx.x;
    const int lane = tid & 63, wid = tid >> 6;
    const float inv_s3 = (float)((double)(3 * H2D) / ssum[0]);
    float a0 = 0.f, a1 = 0.f, a2 = 0.f;
    for (int k = tid; k < H2D; k += 256) {
        const float h = bf2f(H2[(size_t)row * H2D + k]);
        const float q0 = rintf(fminf(1.f, fmaxf(-1.f, w3[k] * inv_s3)));
        const float q1 = rintf(fminf(1.f, fmaxf(-1.f, w3[H2D + k] * inv_s3)));
        const float q2 = rintf(fminf(1.f, fmaxf(-1.f, w3[2 * H2D + k] * inv_s3)));
        a0 += h * q0; a1 += h * q1; a2 += h * q2;
    }
    for (int o = 32; o; o >>= 1) {
        a0 += __shfl_down(a0, o); a1 += __shfl_down(a1, o); a2 += __shfl_down(a2, o);
    }
    __shared__ float r[3][4];
    if (lane == 0) { r[0][wid] = a0; r[1][wid] = a1; r[2][wid] = a2; }
    __syncthreads();
    if (tid < 3) {
        const float s3 = (float)(ssum[0] / (double)(3 * H2D));
        out[(size_t)row * 3 + tid] =
            (r[tid][0] + r[tid][1] + r[tid][2] + r[tid][3]) * s3 + b3[tid];
    }
}

// ---------------- launch ----------------

extern "C" void kernel_launch(void* const* d_in, const int* in_sizes, int n_in,
                              void* d_out, int out_size, void* d_ws, size_t ws_size,
                              hipStream_t stream) {
    const int*   ids = (const int*)d_in[0];
    const float* emb = (const float*)d_in[1];
    const float* w1  = (const float*)d_in[2];
    const float* b1  = (const float*)d_in[3];
    const float* w2  = (const float*)d_in[4];
    const float* b2  = (const float*)d_in[5];
    const float* w3  = (const float*)d_in[6];
    const float* b3  = (const float*)d_in[7];
    const float* g1  = (const float*)d_in[8];
    const float* be1 = (const float*)d_in[9];
    const float* g2  = (const float*)d_in[10];
    const float* be2 = (const float*)d_in[11];
    float* out = (float*)d_out;
    char* ws = (char*)d_ws;

    double*         sums = (double*)(ws + OFF_S);
    unsigned short* X    = (unsigned short*)(ws + OFF_X);
    unsigned short* embh = (unsigned short*)(ws + OFF_EMBH);
    unsigned short* q1   = (unsigned short*)(ws + OFF_Q1);
    unsigned short* q2   = (unsigned short*)(ws + OFF_Q2);
    float*          Cbuf = (float*)(ws + OFF_C);
    unsigned short* H1   = (unsigned short*)(ws + OFF_H1);
    unsigned short* H2   = (unsigned short*)(ws + OFF_H2);

    // phase 1: bf16 table + gather/pool (embh region free after this)
    emb2bf_kernel<<<4096, 256, 0, stream>>>(emb, embh);
    pool_kernel<<<BB / 2, 256, 0, stream>>>(ids, embh, X);

    // phase 2: scales + ternary quant (q1/q2 overlay embh)
    zero_sums<<<1, 64, 0, stream>>>(sums);
    absum_all<<<3096, 256, 0, stream>>>(w1, w2, w3, sums);
    quant_all<<<12288, 256, 0, stream>>>(w1, w2, sums, q1, q2);

    // phase 3: MLP
    gemm_bt<<<dim3(HH / 128, BB / 128), 256, 0, stream>>>(X, q1, Cbuf, BB, HH, EE);
    ln_gelu_kernel<<<BB, 256, 0, stream>>>(Cbuf, sums + 0, (double)HH * (double)EE,
                                           b1, g1, be1, H1, HH);
    gemm_bt<<<dim3(H2D / 128, BB / 128), 256, 0, stream>>>(H1, q2, Cbuf, BB, H2D, HH);
    ln_gelu_kernel<<<BB, 256, 0, stream>>>(Cbuf, sums + 1, (double)H2D * (double)HH,
                                           b2, g2, be2, H2, H2D);
    final_kernel<<<BB, 256, 0, stream>>>(H2, w3, sums + 2, b3, out);
}

// Round 3
// 722.977 us; speedup vs baseline: 1.2143x; 1.0674x over previous
//
#include <hip/hip_runtime.h>
#include <cstdint>
#include <cstddef>

// ---------------- common helpers ----------------

#define GAS __attribute__((address_space(1)))
#define LAS __attribute__((address_space(3)))

typedef __bf16 bf16x8 __attribute__((ext_vector_type(8)));
typedef float  f32x4  __attribute__((ext_vector_type(4)));
typedef unsigned short u16x8 __attribute__((ext_vector_type(8)));

__device__ __forceinline__ unsigned short f2bf(float f) {
    // round-to-nearest-even float -> bf16 bits (finite inputs only)
    unsigned int u = __float_as_uint(f);
    u += 0x7FFFu + ((u >> 16) & 1u);
    return (unsigned short)(u >> 16);
}
__device__ __forceinline__ float bf2f(unsigned short h) {
    return __uint_as_float(((unsigned int)h) << 16);
}

// ---------------- problem constants ----------------
// B=4096, S=128, E=1024, H=4096, H2=2048, NCLS=3, VOCAB=50257
static constexpr int BB = 4096;
static constexpr int SS = 128;
static constexpr int EE = 1024;
static constexpr int HH = 4096;
static constexpr int H2D = 2048;
static constexpr int VOCAB = 50257;

// ---------------- workspace layout (bytes) ----------------
// Phase overlay: embh (bf16 table, 98.2 MiB) is dead after pool_kernel;
// q1/q2/C overlay it. H2 overlays q1/q2 (dead after gemm2).
static constexpr size_t OFF_S    = 0;                          // 3 doubles
static constexpr size_t OFF_X    = 4096;                       // 4096x1024 bf16 = 8 MiB
static constexpr size_t SZ_X     = (size_t)BB * EE * 2;
static constexpr size_t OFF_EMBH = OFF_X + SZ_X;               // 50257x1024 bf16 = 98.2 MiB
static constexpr size_t SZ_EMBH  = (size_t)VOCAB * EE * 2;
static constexpr size_t OFF_Q1   = OFF_EMBH;                   // 4096x1024 bf16 = 8 MiB
static constexpr size_t OFF_Q2   = OFF_Q1 + (size_t)HH * EE * 2;       // 2048x4096 bf16 = 16 MiB
static constexpr size_t OFF_C    = OFF_Q2 + (size_t)H2D * HH * 2;      // 4096x4096 f32 = 64 MiB
static constexpr size_t OFF_H1   = OFF_EMBH + SZ_EMBH;         // 4096x4096 bf16 = 32 MiB
static constexpr size_t OFF_H2   = OFF_Q1;                     // 4096x2048 bf16 = 16 MiB (overlay)
// total ws needed ~ 138.2 MiB

// ---------------- kernels ----------------

__global__ void zero_sums(double* s) {
    if (threadIdx.x < 3) s[threadIdx.x] = 0.0;
}

// fused: fp32 emb -> bf16 table AND abs-sums of w1/w2/w3 (independent streaming work)
__global__ __launch_bounds__(256) void prep_kernel(const float* __restrict__ e,
                                                   unsigned short* __restrict__ o,
                                                   const float* __restrict__ w1,
                                                   const float* __restrict__ w2,
                                                   const float* __restrict__ w3,
                                                   double* __restrict__ sums) {
    const int bid = blockIdx.x;
    const int tid = threadIdx.x;
    if (bid < 4096) {
        // emb -> bf16, 8 elems/thread, grid-stride
        const int n8 = (VOCAB * EE) / 8;
        for (int i = bid * 256 + tid; i < n8; i += 4096 * 256) {
            const float4 v0 = ((const float4*)e)[2 * i];
            const float4 v1 = ((const float4*)e)[2 * i + 1];
            union { unsigned short u[8]; uint4 q; } r;
            r.u[0] = f2bf(v0.x); r.u[1] = f2bf(v0.y); r.u[2] = f2bf(v0.z); r.u[3] = f2bf(v0.w);
            r.u[4] = f2bf(v1.x); r.u[5] = f2bf(v1.y); r.u[6] = f2bf(v1.z); r.u[7] = f2bf(v1.w);
            ((uint4*)o)[i] = r.q;
        }
        return;
    }
    const float* w; int n; double* out; int b0; int nb;
    if (bid < 5120)      { w = w1; n = HH * EE;  out = sums + 0; b0 = bid - 4096; nb = 1024; }
    else if (bid < 7168) { w = w2; n = H2D * HH; out = sums + 1; b0 = bid - 5120; nb = 2048; }
    else                 { w = w3; n = 3 * H2D;  out = sums + 2; b0 = bid - 7168; nb = 24;   }
    const int lane = tid & 63, wid = tid >> 6;
    double acc = 0.0;
    for (int i = b0 * 256 + tid; i < n; i += nb * 256)
        acc += (double)fabsf(w[i]);
    for (int off = 32; off; off >>= 1) acc += __shfl_down(acc, off);
    __shared__ double r[4];
    if (lane == 0) r[wid] = acc;
    __syncthreads();
    if (tid == 0) atomicAdd(out, r[0] + r[1] + r[2] + r[3]);
}

// quantize w1 and w2 to ternary bf16 {-1,0,+1} in one launch
__global__ __launch_bounds__(256) void quant_all(const float* __restrict__ w1,
                                                 const float* __restrict__ w2,
                                                 const double* __restrict__ sums,
                                                 unsigned short* __restrict__ q1,
                                                 unsigned short* __restrict__ q2) {
    const int bid = blockIdx.x;
    const float* w; int n; unsigned short* q; int b0; int nb; double ssum; double dn;
    if (bid < 4096) { w = w1; n = HH * EE;  q = q1; b0 = bid;        nb = 4096; ssum = sums[0]; dn = (double)(HH) * EE; }
    else            { w = w2; n = H2D * HH; q = q2; b0 = bid - 4096; nb = 8192; ssum = sums[1]; dn = (double)(H2D) * HH; }
    const float inv_s = (float)(dn / ssum);
    for (int i = b0 * 256 + threadIdx.x; i < n; i += nb * 256) {
        float t = w[i] * inv_s;
        t = fminf(1.f, fmaxf(-1.f, t));
        q[i] = f2bf(rintf(t));     // exactly -1/0/+1 in bf16
    }
}

// bf16 embedding gather + masked mean pool; 2 output rows per block.
// Ids are counting-sorted per row by table window (id>>10, 2 MiB windows) so the
// whole co-resident grid sweeps the table in ascending order -> per-XCD L2 holds
// the active window and the L2-miss/fabric traffic collapses to ~1 table sweep.
__global__ __launch_bounds__(256) void pool_kernel(const int* __restrict__ ids,
                                                   const unsigned short* __restrict__ embh,
                                                   unsigned short* __restrict__ X) {
    const int tid = threadIdx.x;
    const int row = tid >> 7;           // 0/1 (wave-uniform: 2 waves per row)
    const int t   = tid & 127;
    __shared__ int sid[256];
    __shared__ int sorted_ids[2][128];
    __shared__ int cnt[2][64];
    __shared__ int pos[2][64];
    __shared__ int nz[2];
    sid[tid] = ids[(size_t)blockIdx.x * 256 + tid];
    if (tid < 128) ((int*)cnt)[tid] = 0;
    if (tid < 2) nz[tid] = 0;
    __syncthreads();
    const int myid = sid[tid];
    const int ph = myid >> 10;          // 0..49 (VOCAB/1024)
    atomicAdd(&cnt[row][ph], 1);
    if (myid != 0) atomicAdd(&nz[row], 1);
    __syncthreads();
    if (tid < 2) {
        int s = 0;
        #pragma unroll
        for (int p = 0; p < 64; ++p) { pos[tid][p] = s; s += cnt[tid][p]; }
    }
    __syncthreads();
    const int where = atomicAdd(&pos[row][ph], 1);
    sorted_ids[row][where] = myid;
    __syncthreads();

    const int col = t * 8;
    float a[8] = {};
    #pragma unroll 8
    for (int s = 0; s < 128; ++s) {
        const int id = sorted_ids[row][s];          // broadcast LDS read
        const u16x8 v = *(const u16x8*)(embh + (size_t)id * EE + col);
        #pragma unroll
        for (int j = 0; j < 8; ++j) a[j] += bf2f(v[j]);
    }
    const int c = nz[row];
    const float inv = 1.f / (float)(c ? c : 1);
    u16x8 ov;
    #pragma unroll
    for (int j = 0; j < 8; ++j) ov[j] = f2bf(a[j] * inv);
    const int b = blockIdx.x * 2 + row;
    *(u16x8*)(X + (size_t)b * EE + col) = ov;
}

// C[M,N] = A[M,K] * B[N,K]^T  (bf16 in, fp32 out). M%128==0, N%128==0, K%32==0.
// m97 structure: 128x128 tile, BK=32, global_load_lds width 16, 4 waves x (4x4) 16x16x32 MFMA.
__global__ __launch_bounds__(256) void gemm_bt(const unsigned short* __restrict__ A,
                                               const unsigned short* __restrict__ B,
                                               float* __restrict__ C, int M, int N, int K) {
    __shared__ unsigned short sA[128 * 32];
    __shared__ unsigned short sB[128 * 32];
    const int tid  = threadIdx.x;
    const int wid  = tid >> 6;
    const int lane = tid & 63;
    const int wm = wid >> 1, wn = wid & 1;
    const int quad = lane >> 4;
    const int l16  = lane & 15;
    const int mBase = blockIdx.y * 128;
    const int nBase = blockIdx.x * 128;

    f32x4 acc[4][4] = {};

    const int srow = tid >> 2;            // 0..63
    const int scol = (tid & 3) * 8;       // element col within BK=32
    const size_t aOff0 = (size_t)(mBase + srow) * K + scol;
    const size_t aOff1 = aOff0 + (size_t)64 * K;
    const size_t bOff0 = (size_t)(nBase + srow) * K + scol;
    const size_t bOff1 = bOff0 + (size_t)64 * K;
    unsigned short* ldsA0 = &sA[wid * 512];
    unsigned short* ldsA1 = &sA[2048 + wid * 512];
    unsigned short* ldsB0 = &sB[wid * 512];
    unsigned short* ldsB1 = &sB[2048 + wid * 512];

    for (int k0 = 0; k0 < K; k0 += 32) {
        __syncthreads();
        __builtin_amdgcn_global_load_lds((const GAS void*)(A + aOff0 + k0), (LAS void*)ldsA0, 16, 0, 0);
        __builtin_amdgcn_global_load_lds((const GAS void*)(A + aOff1 + k0), (LAS void*)ldsA1, 16, 0, 0);
        __builtin_amdgcn_global_load_lds((const GAS void*)(B + bOff0 + k0), (LAS void*)ldsB0, 16, 0, 0);
        __builtin_amdgcn_global_load_lds((const GAS void*)(B + bOff1 + k0), (LAS void*)ldsB1, 16, 0, 0);
        __syncthreads();

        bf16x8 af[4], bfr[4];
        #pragma unroll
        for (int i = 0; i < 4; ++i) {
            const int rowA = wm * 64 + i * 16 + l16;
            af[i]  = *(const bf16x8*)(&sA[rowA * 32 + quad * 8]);
            const int rowB = wn * 64 + i * 16 + l16;
            bfr[i] = *(const bf16x8*)(&sB[rowB * 32 + quad * 8]);
        }
        #pragma unroll
        for (int i = 0; i < 4; ++i)
            #pragma unroll
            for (int j = 0; j < 4; ++j)
                acc[i][j] = __builtin_amdgcn_mfma_f32_16x16x32_bf16(af[i], bfr[j], acc[i][j], 0, 0, 0);
    }

    // epilogue: C/D layout col=lane&15, row=(lane>>4)*4+reg
    #pragma unroll
    for (int i = 0; i < 4; ++i) {
        const int row0 = mBase + wm * 64 + i * 16 + quad * 4;
        #pragma unroll
        for (int j = 0; j < 4; ++j) {
            const int col = nBase + wn * 64 + j * 16 + l16;
            #pragma unroll
            for (int r = 0; r < 4; ++r)
                C[(size_t)(row0 + r) * N + col] = acc[i][j][r];
        }
    }
}

// y = C*s + bias; layernorm over row; gelu(exact); write bf16
__global__ __launch_bounds__(256) void ln_gelu_kernel(const float* __restrict__ Cm,
                                                      const double* __restrict__ ssum, double nw,
                                                      const float* __restrict__ bias,
                                                      const float* __restrict__ gamma,
                                                      const float* __restrict__ beta,
                                                      unsigned short* __restrict__ H, int N) {
    __shared__ float buf[4096];
    __shared__ float redS[4], redQ[4];
    const int row = blockIdx.x, tid = threadIdx.x;
    const int lane = tid & 63, wid = tid >> 6;
    const float s = (float)(ssum[0] / nw);
    float ps = 0.f, pq = 0.f;
    for (int c = tid; c < N; c += 256) {
        const float y = Cm[(size_t)row * N + c] * s + bias[c];
        buf[c] = y;
        ps += y; pq += y * y;
    }
    for (int o = 32; o; o >>= 1) { ps += __shfl_down(ps, o); pq += __shfl_down(pq, o); }
    if (lane == 0) { redS[wid] = ps; redQ[wid] = pq; }
    __syncthreads();
    const float sum = redS[0] + redS[1] + redS[2] + redS[3];
    const float sq  = redQ[0] + redQ[1] + redQ[2] + redQ[3];
    const float mu  = sum / (float)N;
    float var = sq / (float)N - mu * mu;
    var = fmaxf(var, 0.f);
    const float inv = rsqrtf(var + 1e-5f);
    for (int c = tid; c < N; c += 256) {
        const float y = (buf[c] - mu) * inv * gamma[c] + beta[c];
        const float g = 0.5f * y * (1.f + erff(y * 0.70710678118654752f));
        H[(size_t)row * N + c] = f2bf(g);
    }
}

// logits[row, 0..2] = H2[row,:] . ternary(w3)[c,:] + b3  (w3 quantized on the fly)
__global__ __launch_bounds__(256) void final_kernel(const unsigned short* __restrict__ H2,
                                                    const float* __restrict__ w3,
                                                    const double* __restrict__ ssum,
                                                    const float* __restrict__ b3,
                                                    float* __restrict__ out) {
    const int row = blockIdx.x, tid = threadIdx.x;
    const int lane = tid & 63, wid = tid >> 6;
    const float inv_s3 = (float)((double)(3 * H2D) / ssum[0]);
    float a0 = 0.f, a1 = 0.f, a2 = 0.f;
    for (int k = tid; k < H2D; k += 256) {
        const float h = bf2f(H2[(size_t)row * H2D + k]);
        const float q0 = rintf(fminf(1.f, fmaxf(-1.f, w3[k] * inv_s3)));
        const float q1 = rintf(fminf(1.f, fmaxf(-1.f, w3[H2D + k] * inv_s3)));
        const float q2 = rintf(fminf(1.f, fmaxf(-1.f, w3[2 * H2D + k] * inv_s3)));
        a0 += h * q0; a1 += h * q1; a2 += h * q2;
    }
    for (int o = 32; o; o >>= 1) {
        a0 += __shfl_down(a0, o); a1 += __shfl_down(a1, o); a2 += __shfl_down(a2, o);
    }
    __shared__ float r[3][4];
    if (lane == 0) { r[0][wid] = a0; r[1][wid] = a1; r[2][wid] = a2; }
    __syncthreads();
    if (tid < 3) {
        const float s3 = (float)(ssum[0] / (double)(3 * H2D));
        out[(size_t)row * 3 + tid] =
            (r[tid][0] + r[tid][1] + r[tid][2] + r[tid][3]) * s3 + b3[tid];
    }
}

// ---------------- launch ----------------

extern "C" void kernel_launch(void* const* d_in, const int* in_sizes, int n_in,
                              void* d_out, int out_size, void* d_ws, size_t ws_size,
                              hipStream_t stream) {
    const int*   ids = (const int*)d_in[0];
    const float* emb = (const float*)d_in[1];
    const float* w1  = (const float*)d_in[2];
    const float* b1  = (const float*)d_in[3];
    const float* w2  = (const float*)d_in[4];
    const float* b2  = (const float*)d_in[5];
    const float* w3  = (const float*)d_in[6];
    const float* b3  = (const float*)d_in[7];
    const float* g1  = (const float*)d_in[8];
    const float* be1 = (const float*)d_in[9];
    const float* g2  = (const float*)d_in[10];
    const float* be2 = (const float*)d_in[11];
    float* out = (float*)d_out;
    char* ws = (char*)d_ws;

    double*         sums = (double*)(ws + OFF_S);
    unsigned short* X    = (unsigned short*)(ws + OFF_X);
    unsigned short* embh = (unsigned short*)(ws + OFF_EMBH);
    unsigned short* q1   = (unsigned short*)(ws + OFF_Q1);
    unsigned short* q2   = (unsigned short*)(ws + OFF_Q2);
    float*          Cbuf = (float*)(ws + OFF_C);
    unsigned short* H1   = (unsigned short*)(ws + OFF_H1);
    unsigned short* H2   = (unsigned short*)(ws + OFF_H2);

    // phase 1: bf16 table + weight abs-sums (fused), then gather/pool
    zero_sums<<<1, 64, 0, stream>>>(sums);
    prep_kernel<<<7192, 256, 0, stream>>>(emb, embh, w1, w2, w3, sums);
    pool_kernel<<<BB / 2, 256, 0, stream>>>(ids, embh, X);

    // phase 2: ternary quant (q1/q2 overlay embh — must be after pool)
    quant_all<<<12288, 256, 0, stream>>>(w1, w2, sums, q1, q2);

    // phase 3: MLP
    gemm_bt<<<dim3(HH / 128, BB / 128), 256, 0, stream>>>(X, q1, Cbuf, BB, HH, EE);
    ln_gelu_kernel<<<BB, 256, 0, stream>>>(Cbuf, sums + 0, (double)HH * (double)EE,
                                           b1, g1, be1, H1, HH);
    gemm_bt<<<dim3(H2D / 128, BB / 128), 256, 0, stream>>>(H1, q2, Cbuf, BB, H2D, HH);
    ln_gelu_kernel<<<BB, 256, 0, stream>>>(Cbuf, sums + 1, (double)H2D * (double)HH,
                                           b2, g2, be2, H2, H2D);
    final_kernel<<<BB, 256, 0, stream>>>(H2, w3, sums + 2, b3, out);
}